// Round 1
// baseline (202.450 us; speedup 1.0000x reference)
//
#include <hip/hip_runtime.h>
#include <hip/hip_bf16.h>
#include <math.h>

// spatialAttention: B=512, P=128, D=64, domain 12x12, W [64,128], out [512,128,64] f32
#define NB 512
#define NP 128
#define ND 64
#define EPSF 1e-5f

// One block per batch b. 256 threads = 4 waves; each wave owns 32 rows (p),
// processed 4 rows at a time with register blocking.
// LDS: hidden[b] f32 (32KB) + W^T bf16 (16KB) + per-wave interleaved
// weights/fused buffer (8KB) + domain/mask (~1KB) = ~58KB -> 2 blocks/CU.
__global__ __launch_bounds__(256, 2) void spatial_attn_kernel(
    const float* __restrict__ hidden,   // [B,P,D]
    const float* __restrict__ dist,     // [B,P,P]
    const float* __restrict__ bear,     // [B,P,P]
    const float* __restrict__ head,     // [B,P,P]
    const float* __restrict__ smask,    // [B,P]
    const float* __restrict__ domain,   // [12,12]
    const float* __restrict__ W,        // [D, 2D] row-major
    const float* __restrict__ bias,     // [D]
    float* __restrict__ out)            // [B,P,D]
{
    __shared__ __align__(16) float s_h[NP][ND];              // 32 KB hidden[b]
    __shared__ __hip_bfloat16 s_Wt[2 * ND][ND];              // 16 KB, s_Wt[k][d] = W[d][k]
    __shared__ __align__(16) float s_w4[4][NP][4];           // 8 KB, [wave][q][row]; reused for fused rows
    __shared__ float s_dom[144];
    __shared__ float s_mask[NP];

    const int b = blockIdx.x;
    const int tid = threadIdx.x;
    const int lane = tid & 63;
    const int wave = tid >> 6;

    // ---- stage hidden[b] (2048 float4, 8 per thread) ----
    {
        const float4* hsrc = (const float4*)(hidden + (size_t)b * NP * ND);
        float4* hdst = (float4*)&s_h[0][0];
        #pragma unroll
        for (int i = 0; i < (NP * ND / 4) / 256; ++i)
            hdst[tid + i * 256] = hsrc[tid + i * 256];
    }
    // ---- stage W transposed as bf16 ----
    {
        #pragma unroll
        for (int i = 0; i < (ND * 2 * ND / 4) / 256; ++i) {
            int idx = tid + i * 256;
            float4 v = ((const float4*)W)[idx];
            int base = idx * 4;
            int d = base >> 7;       // /128
            int k = base & 127;      // %128 (row-aligned: 128 % 4 == 0)
            s_Wt[k][d]     = __float2bfloat16(v.x);
            s_Wt[k + 1][d] = __float2bfloat16(v.y);
            s_Wt[k + 2][d] = __float2bfloat16(v.z);
            s_Wt[k + 3][d] = __float2bfloat16(v.w);
        }
    }
    if (tid < 144) s_dom[tid] = domain[tid];
    if (tid < NP)  s_mask[tid] = smask[b * NP + tid];
    __syncthreads();

    const float bv = bias[lane];
    const size_t rowbase = (size_t)b * NP * NP;

    for (int j = 0; j < 8; ++j) {
        const int p0 = wave * 32 + j * 4;   // this wave's 4 rows

        // ---- phase 1: masked-softmax weights for rows p0..p0+3 ----
        #pragma unroll
        for (int r = 0; r < 4; ++r) {
            const int p = p0 + r;
            const size_t ro = rowbase + (size_t)p * NP;
            // q = lane and q = lane+64 (coalesced)
            float dq0 = dist[ro + lane], dq1 = dist[ro + lane + 64];
            float bq0 = bear[ro + lane], bq1 = bear[ro + lane + 64];
            float hq0 = head[ro + lane], hq1 = head[ro + lane + 64];
            const float mp = s_mask[p];
            const float mq0 = s_mask[lane], mq1 = s_mask[lane + 64];

            // NOTE: true IEEE division by 30.0f to match numpy's floor(x/30)
            // bit-exactly at bin boundaries (reciprocal-multiply can flip a cell).
            int i1 = (int)floorf(hq0 / 30.0f); i1 = i1 < 0 ? 0 : (i1 > 11 ? 11 : i1);
            int i2 = (int)floorf(bq0 / 30.0f); i2 = i2 < 0 ? 0 : (i2 > 11 ? 11 : i2);
            float wv0 = s_dom[i1 * 12 + i2] - dq0;
            bool on0 = (wv0 > 0.0f) && (mp != 0.0f) && (mq0 != 0.0f) && (lane != p);
            float e0 = on0 ? (expf(wv0) + EPSF) : EPSF;

            int k1 = (int)floorf(hq1 / 30.0f); k1 = k1 < 0 ? 0 : (k1 > 11 ? 11 : k1);
            int k2 = (int)floorf(bq1 / 30.0f); k2 = k2 < 0 ? 0 : (k2 > 11 ? 11 : k2);
            float wv1 = s_dom[k1 * 12 + k2] - dq1;
            bool on1 = (wv1 > 0.0f) && (mp != 0.0f) && (mq1 != 0.0f) && ((lane + 64) != p);
            float e1 = on1 ? (expf(wv1) + EPSF) : EPSF;

            float ssum = e0 + e1;
            #pragma unroll
            for (int off = 32; off > 0; off >>= 1)
                ssum += __shfl_xor(ssum, off, 64);
            float inv = 1.0f / (ssum + EPSF);
            s_w4[wave][lane][r]      = e0 * inv;
            s_w4[wave][lane + 64][r] = e1 * inv;
        }
        // same-wave LDS write->read dependency: compiler inserts lgkmcnt waits

        // ---- phase 2: weighted_hidden = weights @ hidden  (lane = d) ----
        float a0 = 0.f, a1 = 0.f, a2 = 0.f, a3 = 0.f;
        #pragma unroll 4
        for (int q = 0; q < NP; ++q) {
            const float4 wq = *(const float4*)&s_w4[wave][q][0];  // broadcast
            const float hv = s_h[q][lane];                        // conflict-free
            a0 = fmaf(wq.x, hv, a0);
            a1 = fmaf(wq.y, hv, a1);
            a2 = fmaf(wq.z, hv, a2);
            a3 = fmaf(wq.w, hv, a3);
        }

        // ---- phase 3: build fused rows [wh | hidden_row] into s_w4 ----
        *(float4*)&s_w4[wave][lane][0] = make_float4(a0, a1, a2, a3);
        {
            float f0 = s_h[p0 + 0][lane];
            float f1 = s_h[p0 + 1][lane];
            float f2 = s_h[p0 + 2][lane];
            float f3 = s_h[p0 + 3][lane];
            *(float4*)&s_w4[wave][64 + lane][0] = make_float4(f0, f1, f2, f3);
        }

        // ---- phase 4: out = tanh(fused @ W^T + b)  (lane = d) ----
        float o0 = bv, o1 = bv, o2 = bv, o3 = bv;
        #pragma unroll 4
        for (int k = 0; k < 2 * ND; ++k) {
            const float4 f = *(const float4*)&s_w4[wave][k][0];   // broadcast
            const float wt = __bfloat162float(s_Wt[k][lane]);     // conflict-free
            o0 = fmaf(f.x, wt, o0);
            o1 = fmaf(f.y, wt, o1);
            o2 = fmaf(f.z, wt, o2);
            o3 = fmaf(f.w, wt, o3);
        }

        float* orow = out + ((size_t)b * NP + p0) * ND;
        orow[lane]          = tanhf(o0);
        orow[ND + lane]     = tanhf(o1);
        orow[2 * ND + lane] = tanhf(o2);
        orow[3 * ND + lane] = tanhf(o3);
    }
}

extern "C" void kernel_launch(void* const* d_in, const int* in_sizes, int n_in,
                              void* d_out, int out_size, void* d_ws, size_t ws_size,
                              hipStream_t stream) {
    const float* hidden = (const float*)d_in[0];
    const float* dist   = (const float*)d_in[1];
    const float* bear   = (const float*)d_in[2];
    const float* head   = (const float*)d_in[3];
    const float* smask  = (const float*)d_in[4];
    const float* domain = (const float*)d_in[5];
    const float* W      = (const float*)d_in[6];
    const float* bias   = (const float*)d_in[7];
    float* out = (float*)d_out;

    spatial_attn_kernel<<<dim3(NB), dim3(256), 0, stream>>>(
        hidden, dist, bear, head, smask, domain, W, bias, out);
}

// Round 2
// 156.667 us; speedup vs baseline: 1.2922x; 1.2922x over previous
//
#include <hip/hip_runtime.h>
#include <hip/hip_bf16.h>
#include <math.h>

// spatialAttention: B=512, P=128, D=64, domain 12x12, W [64,128], out [512,128,64] f32
#define NB 512
#define NP 128
#define ND 64
#define EPSF 1e-5f
// bf16-element row stride for MFMA-read LDS arrays: 136 elems = 272 B.
// 272 is a multiple of 16 -> every short8 frag read is 16B-aligned.
// bank_start(lane m) = (m*68 + quad*4) % 32 = (m*4 + quad*4) % 32 -> lanes m and
// m+8 alias (2-way, free per m136); no 8/16-way conflicts.
#define SW 136

typedef __attribute__((ext_vector_type(8))) short short8;   // 8 bf16 = 4 VGPRs
typedef __attribute__((ext_vector_type(4))) float f32x4;    // MFMA accumulator

__device__ __forceinline__ short f2bf(float x) {
    __hip_bfloat16 h = __float2bfloat16(x);
    return *reinterpret_cast<short*>(&h);
}

// One block per batch. 4 waves; wave w owns output rows [32w, 32w+32).
// Single __syncthreads (after staging); everything else is wave-local:
//   phase 1: 32 row-softmaxes -> bf16 weights in s_w   (global streaming, high MLP)
//   phase 2: wh = w @ h        via MFMA (K=128), wave-local rows
//   fused  : s_w rows become [wh | h] (bf16), wave-local overwrite
//   phase 3: out = tanh(fused @ W^T + b) via MFMA (K=128)
__global__ __launch_bounds__(256, 2) void spatial_attn_kernel(
    const float* __restrict__ hidden,   // [B,P,D]
    const float* __restrict__ dist,     // [B,P,P]
    const float* __restrict__ bear,     // [B,P,P]
    const float* __restrict__ head,     // [B,P,P]
    const float* __restrict__ smask,    // [B,P]
    const float* __restrict__ domain,   // [12,12]
    const float* __restrict__ W,        // [D, 2D] row-major
    const float* __restrict__ bias,     // [D]
    float* __restrict__ out)            // [B,P,D]
{
    __shared__ __align__(16) short s_w[NP * SW];   // 34816 B: weights, then [wh|h]
    __shared__ __align__(16) short s_hT[ND * SW];  // 17408 B: s_hT[d][q] = h[q][d]
    __shared__ __align__(16) short s_Wm[ND * SW];  // 17408 B: s_Wm[d][k] = W[d][k]
    __shared__ float s_dom[144];
    __shared__ float s_mask[NP];

    const int b    = blockIdx.x;
    const int tid  = threadIdx.x;
    const int lane = tid & 63;
    const int wave = tid >> 6;
    const int quad = lane >> 4;
    const int l16  = lane & 15;

    // ---- stage hidden^T as bf16 (transpose during store) ----
    {
        const float4* hsrc = (const float4*)(hidden + (size_t)b * NP * ND);
        #pragma unroll
        for (int i = 0; i < 8; ++i) {
            int idx = tid + i * 256;          // float4 index, 2048 total
            float4 v = hsrc[idx];
            int q = idx >> 4;                 // element/64
            int d = (idx & 15) * 4;           // element%64, 4-aligned
            s_hT[(d + 0) * SW + q] = f2bf(v.x);
            s_hT[(d + 1) * SW + q] = f2bf(v.y);
            s_hT[(d + 2) * SW + q] = f2bf(v.z);
            s_hT[(d + 3) * SW + q] = f2bf(v.w);
        }
    }
    // ---- stage W as bf16 row-major [d][k] ----
    {
        #pragma unroll
        for (int i = 0; i < 8; ++i) {
            int idx = tid + i * 256;          // 2048 float4
            float4 v = ((const float4*)W)[idx];
            int d = idx >> 5;                 // element/128
            int k = (idx & 31) * 4;           // element%128, 4-aligned
            short4 s4;
            s4.x = f2bf(v.x); s4.y = f2bf(v.y); s4.z = f2bf(v.z); s4.w = f2bf(v.w);
            *(short4*)&s_Wm[d * SW + k] = s4; // 8B-aligned ds_write_b64
        }
    }
    if (tid < 144) s_dom[tid] = domain[tid];
    if (tid < NP)  s_mask[tid] = smask[b * NP + tid];
    __syncthreads();   // the only block-wide barrier

    const int R0 = wave * 32;
    const size_t rowbase = (size_t)b * NP * NP;
    const float mq0 = s_mask[lane], mq1 = s_mask[lane + 64];

    // ---- phase 1: masked-softmax weights for all 32 own rows ----
    for (int j = 0; j < 8; ++j) {
        #pragma unroll
        for (int r = 0; r < 4; ++r) {
            const int p = R0 + j * 4 + r;
            const size_t ro = rowbase + (size_t)p * NP;
            float dq0 = dist[ro + lane], dq1 = dist[ro + lane + 64];
            float bq0 = bear[ro + lane], bq1 = bear[ro + lane + 64];
            float hq0 = head[ro + lane], hq1 = head[ro + lane + 64];
            const float mp = s_mask[p];

            // true IEEE division by 30.0f: matches numpy floor(x/30) at bin edges
            int i1 = (int)floorf(hq0 / 30.0f); i1 = i1 < 0 ? 0 : (i1 > 11 ? 11 : i1);
            int i2 = (int)floorf(bq0 / 30.0f); i2 = i2 < 0 ? 0 : (i2 > 11 ? 11 : i2);
            float wv0 = s_dom[i1 * 12 + i2] - dq0;
            bool on0 = (wv0 > 0.0f) && (mp != 0.0f) && (mq0 != 0.0f) && (lane != p);
            float e0 = on0 ? (expf(wv0) + EPSF) : EPSF;

            int k1 = (int)floorf(hq1 / 30.0f); k1 = k1 < 0 ? 0 : (k1 > 11 ? 11 : k1);
            int k2 = (int)floorf(bq1 / 30.0f); k2 = k2 < 0 ? 0 : (k2 > 11 ? 11 : k2);
            float wv1 = s_dom[k1 * 12 + k2] - dq1;
            bool on1 = (wv1 > 0.0f) && (mp != 0.0f) && (mq1 != 0.0f) && ((lane + 64) != p);
            float e1 = on1 ? (expf(wv1) + EPSF) : EPSF;

            float ssum = e0 + e1;
            #pragma unroll
            for (int off = 32; off > 0; off >>= 1)
                ssum += __shfl_xor(ssum, off, 64);
            float inv = 1.0f / (ssum + EPSF);
            // consecutive-lane bf16 writes: conflict-free
            s_w[p * SW + lane]      = f2bf(e0 * inv);
            s_w[p * SW + lane + 64] = f2bf(e1 * inv);
        }
    }

    // ---- phase 2: wh = w @ h, wave-local 32x64 tile via MFMA ----
    // A[m][k]: m=l16 (+16*ti), k=quad*8+j  from s_w rows (own)
    // B[k][n]: k=quad*8+j, n=l16 (+16*tj)  from s_hT[n][k]
    f32x4 acc[2][4];
    #pragma unroll
    for (int ti = 0; ti < 2; ++ti)
        #pragma unroll
        for (int tj = 0; tj < 4; ++tj)
            acc[ti][tj] = (f32x4){0.f, 0.f, 0.f, 0.f};

    #pragma unroll
    for (int kb = 0; kb < 4; ++kb) {
        const int ko = kb * 32 + quad * 8;
        short8 a0 = *(const short8*)&s_w[(R0 + l16) * SW + ko];
        short8 a1 = *(const short8*)&s_w[(R0 + 16 + l16) * SW + ko];
        #pragma unroll
        for (int tj = 0; tj < 4; ++tj) {
            short8 bf = *(const short8*)&s_hT[(tj * 16 + l16) * SW + ko];
            acc[0][tj] = __builtin_amdgcn_mfma_f32_16x16x32_bf16(a0, bf, acc[0][tj], 0, 0, 0);
            acc[1][tj] = __builtin_amdgcn_mfma_f32_16x16x32_bf16(a1, bf, acc[1][tj], 0, 0, 0);
        }
    }

    // ---- build fused rows [wh | h] in s_w (own rows only; wave-local) ----
    // C/D layout: row = quad*4 + reg, col = l16
    #pragma unroll
    for (int ti = 0; ti < 2; ++ti)
        #pragma unroll
        for (int tj = 0; tj < 4; ++tj)
            #pragma unroll
            for (int r = 0; r < 4; ++r) {
                int row = R0 + ti * 16 + quad * 4 + r;
                s_w[row * SW + tj * 16 + l16] = f2bf(acc[ti][tj][r]);
            }
    {
        const float* hb = hidden + (size_t)b * NP * ND;
        #pragma unroll 4
        for (int i = 0; i < 32; ++i) {   // L2-warm coalesced re-read of own rows
            float hv = hb[(size_t)(R0 + i) * ND + lane];
            s_w[(R0 + i) * SW + 64 + lane] = f2bf(hv);
        }
    }

    // ---- phase 3: out = tanh(fused @ W^T + b) via MFMA (K=128) ----
    // B[k][n=d] = W[d][k] = s_Wm[d][k]: lane n reads k-contiguous -> b128
    f32x4 acc2[2][4];
    #pragma unroll
    for (int ti = 0; ti < 2; ++ti)
        #pragma unroll
        for (int tj = 0; tj < 4; ++tj)
            acc2[ti][tj] = (f32x4){0.f, 0.f, 0.f, 0.f};

    #pragma unroll
    for (int kb = 0; kb < 4; ++kb) {
        const int ko = kb * 32 + quad * 8;
        short8 a0 = *(const short8*)&s_w[(R0 + l16) * SW + ko];
        short8 a1 = *(const short8*)&s_w[(R0 + 16 + l16) * SW + ko];
        #pragma unroll
        for (int tj = 0; tj < 4; ++tj) {
            short8 bf = *(const short8*)&s_Wm[(tj * 16 + l16) * SW + ko];
            acc2[0][tj] = __builtin_amdgcn_mfma_f32_16x16x32_bf16(a0, bf, acc2[0][tj], 0, 0, 0);
            acc2[1][tj] = __builtin_amdgcn_mfma_f32_16x16x32_bf16(a1, bf, acc2[1][tj], 0, 0, 0);
        }
    }

    float bvals[4];
    #pragma unroll
    for (int tj = 0; tj < 4; ++tj) bvals[tj] = bias[tj * 16 + l16];

    float* ob = out + (size_t)b * NP * ND;
    #pragma unroll
    for (int ti = 0; ti < 2; ++ti)
        #pragma unroll
        for (int tj = 0; tj < 4; ++tj)
            #pragma unroll
            for (int r = 0; r < 4; ++r) {
                int row = R0 + ti * 16 + quad * 4 + r;
                ob[(size_t)row * ND + tj * 16 + l16] = tanhf(acc2[ti][tj][r] + bvals[tj]);
            }
}

extern "C" void kernel_launch(void* const* d_in, const int* in_sizes, int n_in,
                              void* d_out, int out_size, void* d_ws, size_t ws_size,
                              hipStream_t stream) {
    const float* hidden = (const float*)d_in[0];
    const float* dist   = (const float*)d_in[1];
    const float* bear   = (const float*)d_in[2];
    const float* head   = (const float*)d_in[3];
    const float* smask  = (const float*)d_in[4];
    const float* domain = (const float*)d_in[5];
    const float* W      = (const float*)d_in[6];
    const float* bias   = (const float*)d_in[7];
    float* out = (float*)d_out;

    spatial_attn_kernel<<<dim3(NB), dim3(256), 0, stream>>>(
        hidden, dist, bear, head, smask, domain, W, bias, out);
}